// Round 19
// baseline (561.359 us; speedup 1.0000x reference)
//
#include <hip/hip_runtime.h>
#include <hip/hip_bf16.h>

// Problem constants: B=128, T=512, V=50000, E=100, U=128, K=32
#define B_  128
#define T_  512
#define V_  50000
#define VP  50016   // V padded to 32
#define E_  100
#define U_  128
#define K_  32
#define G4  512   // 4*U
#define KP  128   // padded K for MFMA GEMM

typedef _Float16 h2_t __attribute__((ext_vector_type(2)));
typedef _Float16 f16x8 __attribute__((ext_vector_type(8)));
typedef __fp16   h2raw_t __attribute__((ext_vector_type(2)));
typedef short    bf16x8 __attribute__((ext_vector_type(8)));
typedef float    f32x4  __attribute__((ext_vector_type(4)));

// LDS-only barrier (T4): orders LDS ops without draining vmem.
#define LGKM_BARRIER() do {                                   \
    asm volatile("s_waitcnt lgkmcnt(0)" ::: "memory");        \
    __builtin_amdgcn_s_barrier();                             \
    asm volatile("" ::: "memory");                            \
} while (0)

__device__ __forceinline__ h2_t pk2(float a, float b) {
    h2raw_t r = __builtin_amdgcn_cvt_pkrtz(a, b);
    union { h2raw_t r; h2_t h; } u; u.r = r; return u.h;
}

#if __has_builtin(__builtin_amdgcn_rcpf)
__device__ __forceinline__ float rcp_f(float x) { return __builtin_amdgcn_rcpf(x); }
#else
__device__ __forceinline__ float rcp_f(float x) { return 1.f / x; }
#endif

__device__ __forceinline__ unsigned short bf16_bits(float v) {
    __hip_bfloat16 b = __float2bfloat16(v);
    union { __hip_bfloat16 b; unsigned short s; } u; u.b = b; return u.s;
}
__device__ __forceinline__ float bf2f(unsigned short u) {
    union { unsigned int i; float f; } x; x.i = ((unsigned int)u) << 16; return x.f;
}

// ---------------------------------------------------------------------------
// Kernel A0: pack Bb[n][k] (n-major, K padded to 128, bf16) from Wk_f|Wk_b.
// ---------------------------------------------------------------------------
__global__ __launch_bounds__(128) void pack_b_kernel(
    const float* __restrict__ Wk_f, const float* __restrict__ Wk_b,
    __hip_bfloat16* __restrict__ Bb)
{
    const int n = blockIdx.x;     // 0..1023
    const int k = threadIdx.x;    // 0..127
    float v = 0.f;
    if (k < E_) v = (n < 512) ? Wk_f[k * 512 + n] : Wk_b[k * 512 + (n - 512)];
    Bb[n * KP + k] = __float2bfloat16(v);
}

// ---------------------------------------------------------------------------
// Kernel A: proj[v][1024] = emb[v] @ [Wk_f | Wk_b] + [b_f | b_b], bf16.
//   OCCUPANCY SPLIT: A_st no longer aliases C_lds, and the epilogue tile
//   is halved (8 n-groups of 128 cols, C_lds[64][132]): 17.4 + 33.8 =
//   51.2 KB -> 3 blocks/CU (was 68.6 KB -> 2). Same MFMA count and the
//   measured-good LDS epilogue + coalesced dword stores.
//   Wave layout: mq = wv>>1 (16-row m-tile), chf = wv&1 (64-col half).
// ---------------------------------------------------------------------------
__global__ __launch_bounds__(512) void proj_mfma_kernel(
    const float* __restrict__ emb,
    const __hip_bfloat16* __restrict__ Bb,
    const float* __restrict__ b_f, const float* __restrict__ b_b,
    __hip_bfloat16* __restrict__ proj)
{
    const int r0   = blockIdx.x * 64;
    const int tid  = threadIdx.x;
    const int wv   = tid >> 6;
    const int lane = tid & 63;
    const int quad = lane >> 4;
    const int l16  = lane & 15;
    const int mq   = wv >> 1;      // m-tile: rows [mq*16, mq*16+16)
    const int chf  = wv & 1;       // col half: cols [chf*64, chf*64+64)

    __shared__ __align__(16) unsigned short A_st[64][136];  // 17.4 KB
    __shared__ __align__(16) float C_lds[64][132];          // 33.8 KB

    for (int idx = tid; idx < 64 * 64; idx += 512) {
        int r = idx >> 6, kk = idx & 63;
        int vr = r0 + r; if (vr >= V_) vr = V_ - 1;   // clamp: no OOB reads
        unsigned int w = 0;
        if (kk < 50) {
            float2 v = *(const float2*)(emb + (long long)vr * E_ + 2 * kk);
            w = ((unsigned int)bf16_bits(v.y) << 16) | bf16_bits(v.x);
        }
        *(unsigned int*)&A_st[r][2 * kk] = w;
    }
    LGKM_BARRIER();

    bf16x8 af[4];
    #pragma unroll
    for (int kc = 0; kc < 4; ++kc)
        af[kc] = *(const bf16x8*)&A_st[mq * 16 + l16][kc * 32 + quad * 8];

    const unsigned short* Bu = (const unsigned short*)Bb;

    for (int ng = 0; ng < 8; ++ng) {
        const int n0 = ng * 128;

        bf16x8 bfr[4][4];
        #pragma unroll
        for (int nt = 0; nt < 4; ++nt)
            #pragma unroll
            for (int kc = 0; kc < 4; ++kc)
                bfr[nt][kc] = *(const bf16x8*)(Bu +
                    (n0 + chf * 64 + nt * 16 + l16) * KP + kc * 32 + quad * 8);

        f32x4 acc[4];
        #pragma unroll
        for (int nt = 0; nt < 4; ++nt)
            acc[nt] = (f32x4){0.f, 0.f, 0.f, 0.f};

        #pragma unroll
        for (int nt = 0; nt < 4; ++nt)
            #pragma unroll
            for (int kc = 0; kc < 4; ++kc)
                acc[nt] = __builtin_amdgcn_mfma_f32_16x16x32_bf16(
                    af[kc], bfr[nt][kc], acc[nt], 0, 0, 0);

        #pragma unroll
        for (int nt = 0; nt < 4; ++nt)
            #pragma unroll
            for (int v = 0; v < 4; ++v)
                C_lds[mq * 16 + quad * 4 + v][chf * 64 + nt * 16 + l16] =
                    acc[nt][v];
        LGKM_BARRIER();

        const float* bias = (n0 < 512) ? b_f : b_b;
        const int nbase = n0 & 511;
        for (int idx = tid; idx < 64 * 64; idx += 512) {
            int r = idx >> 6, cc = (idx & 63) * 2;
            float v0 = C_lds[r][cc]     + bias[nbase + cc];
            float v1 = C_lds[r][cc + 1] + bias[nbase + cc + 1];
            unsigned int w = ((unsigned int)bf16_bits(v1) << 16) | bf16_bits(v0);
            int row = r0 + r; if (row >= VP) row = VP - 1;  // pad row, never read
            *(unsigned int*)(proj + (long long)row * 1024 + n0 + cc) = w;
        }
        LGKM_BARRIER();
    }
}

// ---------------------------------------------------------------------------
// Kernel B: LSTM with fused em partials (R17-EXACT: ring 16, em burst every
//   2 groups on waves 0-3, xk added after MFMA — measured 257 us / 514 total).
// ---------------------------------------------------------------------------
__device__ __forceinline__ float sigmoid_f(float x) {
    return rcp_f(1.f + __expf(-x));
}
__device__ __forceinline__ float tanh_f(float x) {
    return 1.f - 2.f * rcp_f(__expf(2.f * x) + 1.f);
}

__global__ __launch_bounds__(512, 1) void lstm_kernel(
    const __hip_bfloat16* __restrict__ proj,
    const int* __restrict__ tokens,
    const float* __restrict__ Wr_f, const float* __restrict__ Wr_b,
    const float* __restrict__ ck,
    float* __restrict__ em_f, float* __restrict__ em_bw)
{
    const int bid  = blockIdx.x;      // 0..63
    const int dir  = bid >> 5;
    const int b0   = (bid & 31) * 4;  // this block's 4 chains
    const int tid  = threadIdx.x;
    const int w    = tid >> 6;        // wave 0..7 -> units [16w, 16w+16)
    const int lane = tid & 63;
    const int quad = lane >> 4;       // = chain index within block
    const int l16  = lane & 15;
    const int unit = 16 * w + l16;

    const float* Wr = dir ? Wr_b : Wr_f;
    float* eout = dir ? em_bw : em_f;

    // B-frags: wb[g][kc]; element j = Wr[kc*32+quad*8+j][g*128 + unit]
    union uf16 { f16x8 v; h2_t p[4]; };
    f16x8 wb[4][4];
    #pragma unroll
    for (int gq = 0; gq < 4; ++gq) {
        const int col = gq * 128 + unit;
        #pragma unroll
        for (int kc = 0; kc < 4; ++kc) {
            const int k0 = kc * 32 + quad * 8;
            uf16 u;
            #pragma unroll
            for (int jj = 0; jj < 4; ++jj)
                u.p[jj] = pk2(Wr[(k0 + 2 * jj)     * G4 + col],
                              Wr[(k0 + 2 * jj + 1) * G4 + col]);
            wb[gq][kc] = u.v;
        }
    }

    // ck B-frags for the em MFMA (waves 0-3): k-half kh = w&1;
    // col = kh*16+l16; k = dir*128 + (kc*32+quad*8+j). ck is [256][32].
    f16x8 ckb[4];
    const int kh = w & 1;
    const int gs = w >> 1;            // group-pair half (0 -> t4-1, 1 -> t4)
    if (w < 4) {
        #pragma unroll
        for (int kc = 0; kc < 4; ++kc) {
            const int k0 = dir * 128 + kc * 32 + quad * 8;
            uf16 u;
            #pragma unroll
            for (int jj = 0; jj < 4; ++jj)
                u.p[jj] = pk2(ck[(k0 + 2 * jj)     * K_ + kh * 16 + l16],
                              ck[(k0 + 2 * jj + 1) * K_ + kh * 16 + l16]);
            ckb[kc] = u.v;
        }
    }

    // h ring: [16][chain][144 f16] (288B rows ≡ 8 banks); step t reads buf
    // t&15, writes buf (t+1)&15; group g's h lands in bufs (4g+1..4g+4)&15.
    __shared__ __align__(16) _Float16      h_lds[16][4][144];  // 18.4 KB
    // xk double-buffer: [buf][chain][520 u16] (1040B rows)
    __shared__ __align__(16) unsigned short xkb[2][4][520];    // 8.3 KB
    // token table for this block's 4 chains, time-reversed for dir=1
    __shared__ unsigned short tok_lds[4][512];                 // 4 KB

    for (int idx = tid; idx < 4 * 512; idx += 512) {
        int chain = idx >> 9, tt = idx & 511;
        int tsrc = dir ? (T_ - 1 - tt) : tt;
        tok_lds[chain][tt] = (unsigned short)tokens[(b0 + chain) * T_ + tsrc];
    }
    for (int idx = tid; idx < 4 * 144; idx += 512)
        ((_Float16*)h_lds[0])[idx] = (_Float16)0.f;
    __syncthreads();

    // staging mapping: chain sc, dword-column sj (cols 2sj,2sj+1 and +256)
    const int sc = tid >> 7;          // 0..3
    const int sj = tid & 127;         // 0..127
    const unsigned short* prbase = (const unsigned short*)proj + dir * 512;

    // prefetch ring: v[d] holds the step whose index ≡ d (mod 4)
    int v[4][2];
    #pragma unroll
    for (int d = 0; d < 4; ++d) {
        int tk = tok_lds[sc][d];
        const unsigned int* p32 = (const unsigned int*)(prbase + (size_t)tk * 1024);
        v[d][0] = p32[sj];
        v[d][1] = p32[sj + 128];
    }
    // publish step 0 into xkb[0]
    *(unsigned int*)&xkb[0][sc][2 * sj]       = v[0][0];
    *(unsigned int*)&xkb[0][sc][2 * sj + 256] = v[0][1];
    __syncthreads();

    float c = 0.f;

    for (int t4 = 0; t4 < T_ / 4; ++t4) {
        #pragma unroll
        for (int u = 0; u < 4; ++u) {
            const int t  = t4 * 4 + u;
            const int cb = u & 1, nb = cb ^ 1;   // xk parity buffers
            const int hr = t & 15;               // h ring read buf
            const int hw = (t + 1) & 15;         // h ring write buf

            // (1) LDS reads: A-frag (4 chains via l16>>2) + xk (4 gates)
            f16x8 a[4];
            #pragma unroll
            for (int kc = 0; kc < 4; ++kc)
                a[kc] = *(const f16x8*)&h_lds[hr][l16 >> 2][kc * 32 + quad * 8];
            unsigned short xk[4];
            #pragma unroll
            for (int gq = 0; gq < 4; ++gq)
                xk[gq] = xkb[cb][quad][gq * 128 + unit];

            // (2) issue staging loads for step t+4 into v[u]
            {
                int tnx = t + 4; if (tnx > T_ - 1) tnx = T_ - 1;
                int tk = tok_lds[sc][tnx];
                const unsigned int* p32 =
                    (const unsigned int*)(prbase + (size_t)tk * 1024);
                v[u][0] = p32[sj];
                v[u][1] = p32[sj + 128];
            }

            // (3) MFMA: z for 4 chains (chain = C-row>>2 = quad)
            f32x4 acc[4];
            #pragma unroll
            for (int gq = 0; gq < 4; ++gq)
                acc[gq] = (f32x4){0.f, 0.f, 0.f, 0.f};
            #pragma unroll
            for (int gq = 0; gq < 4; ++gq)
                #pragma unroll
                for (int kc = 0; kc < 4; ++kc)
                    acc[gq] = __builtin_amdgcn_mfma_f32_16x16x32_f16(
                        a[kc], wb[gq][kc], acc[gq], 0, 0, 0);

            // (4) gates: ONE (chain=quad, unit) per lane
            float zi = acc[0][0] + bf2f(xk[0]);
            float zf = acc[1][0] + bf2f(xk[1]);
            float zg = acc[2][0] + bf2f(xk[2]);
            float zo = acc[3][0] + bf2f(xk[3]);
            c = sigmoid_f(zf) * c + sigmoid_f(zi) * tanh_f(zg);
            float h = sigmoid_f(zo) * tanh_f(c);
            h_lds[hw][quad][unit] = (_Float16)h;

            // (5) publish v[(u+1)&3] (loaded 3 steps ago) for step t+1
            {
                const int pw = (u + 1) & 3;
                *(unsigned int*)&xkb[nb][sc][2 * sj]       = v[pw][0];
                *(unsigned int*)&xkb[nb][sc][2 * sj + 256] = v[pw][1];
            }

            // (6) LDS-only barrier: vmem stays in flight (T4)
            LGKM_BARRIER();
        }

        // ---- fused em partial, every 2 groups on waves 0-3 ----
        // wave w: group g' = t4-1+gs, k-half kh. Reads bufs
        // (4g'+1..4g'+4)&15 — not rewritten for 2 more groups.
        if ((t4 & 1) && w < 4) {
            const int gp   = t4 - 1 + gs;
            const int d    = l16 >> 2;           // step-in-group of A row
            const int ch   = l16 & 3;            // chain of A row
            const int rbuf = (4 * gp + 1 + d) & 15;
            f16x8 ea[4];
            #pragma unroll
            for (int kc = 0; kc < 4; ++kc)
                ea[kc] = *(const f16x8*)&h_lds[rbuf][ch][kc * 32 + quad * 8];
            f32x4 e = (f32x4){0.f, 0.f, 0.f, 0.f};
            #pragma unroll
            for (int kc = 0; kc < 4; ++kc)
                e = __builtin_amdgcn_mfma_f32_16x16x32_f16(
                    ea[kc], ckb[kc], e, 0, 0, 0);
            // C: row = quad*4+v -> (step d=quad, chain=v); col = l16
            const int step = gp * 4 + quad;
            const int tte  = dir ? (T_ - 1 - step) : step;
            #pragma unroll
            for (int vv = 0; vv < 4; ++vv)
                eout[((size_t)(b0 + vv) * T_ + tte) * K_ + (kh << 4) + l16] =
                    e[vv];
        }
    }
}

// ---------------------------------------------------------------------------
// Kernel D: CRF logZ — linear-space chain, tree-reassociated alpha update
//   (R12/R14 measured-good form: 16 shfl + 4x4-deep fma tree + xor combine).
// ---------------------------------------------------------------------------
#define PF_ 8
__global__ __launch_bounds__(64) void crf_kernel(
    const float* __restrict__ em_f, const float* __restrict__ em_bw,
    const float* __restrict__ cb,
    const float* __restrict__ trans,
    float* __restrict__ out)
{
    const int b    = blockIdx.x;
    const int lane = threadIdx.x;
    const int k    = lane & 31;
    const int half = lane >> 5;

    float etr[16];
    #pragma unroll
    for (int i = 0; i < 16; ++i)
        etr[i] = __expf(trans[(half * 16 + i) * K_ + k]);

    const float cbk = cb[k];
    const float* ef = em_f  + (long long)b * T_ * K_;
    const float* eb = em_bw + (long long)b * T_ * K_;

    float ep[PF_];
    #pragma unroll
    for (int d = 0; d < PF_; ++d)
        ep[d] = ef[d * K_ + k] + eb[d * K_ + k] + cbk;

    float w = 0.f;    // linear-space alpha, scaled
    float L = 0.f;    // accumulated log-scale
    for (int tb = 0; tb < T_; tb += PF_) {
        float en[PF_];
        if (tb + PF_ < T_) {
            #pragma unroll
            for (int d = 0; d < PF_; ++d)
                en[d] = ef[(tb + PF_ + d) * K_ + k] +
                        eb[(tb + PF_ + d) * K_ + k] + cbk;
        } else {
            #pragma unroll
            for (int d = 0; d < PF_; ++d) en[d] = 0.f;
        }

        float eem[PF_];
        #pragma unroll
        for (int d = 0; d < PF_; ++d) eem[d] = __expf(ep[d]);

        #pragma unroll
        for (int d = 0; d < PF_; ++d) {
            if (tb + d == 0) {
                w = eem[d];
            } else {
                // 4 independent 4-deep fma chains (tree combine)
                float a0 = 0.f, a1 = 0.f, a2 = 0.f, a3 = 0.f;
                #pragma unroll
                for (int i = 0; i < 4; ++i)
                    a0 = fmaf(__shfl(w, half * 16 + i,      64), etr[i],      a0);
                #pragma unroll
                for (int i = 0; i < 4; ++i)
                    a1 = fmaf(__shfl(w, half * 16 + 4 + i,  64), etr[4 + i],  a1);
                #pragma unroll
                for (int i = 0; i < 4; ++i)
                    a2 = fmaf(__shfl(w, half * 16 + 8 + i,  64), etr[8 + i],  a2);
                #pragma unroll
                for (int i = 0; i < 4; ++i)
                    a3 = fmaf(__shfl(w, half * 16 + 12 + i, 64), etr[12 + i], a3);
                float acc = (a0 + a1) + (a2 + a3);
                acc += __shfl_xor(acc, 32, 64);
                w = acc * eem[d];
            }
        }

        {
            float w0 = __shfl(w, 0, 64);
            w *= rcp_f(w0);
            L += __logf(w0);
        }

        #pragma unroll
        for (int d = 0; d < PF_; ++d) ep[d] = en[d];
    }

    float s = w;
    #pragma unroll
    for (int d = 1; d < 32; d <<= 1)
        s += __shfl_xor(s, d, 64);
    if (lane == 0) out[b] = L + __logf(s);
}

// ---------------------------------------------------------------------------
extern "C" void kernel_launch(void* const* d_in, const int* in_sizes, int n_in,
                              void* d_out, int out_size, void* d_ws, size_t ws_size,
                              hipStream_t stream)
{
    const int*   tokens = (const int*)  d_in[0];
    const float* emb    = (const float*)d_in[1];
    const float* Wk_f   = (const float*)d_in[2];
    const float* Wr_f   = (const float*)d_in[3];
    const float* b_f    = (const float*)d_in[4];
    const float* Wk_b   = (const float*)d_in[5];
    const float* Wr_b   = (const float*)d_in[6];
    const float* b_b    = (const float*)d_in[7];
    const float* ck     = (const float*)d_in[8];
    const float* cb     = (const float*)d_in[9];
    const float* trans  = (const float*)d_in[10];
    float* out = (float*)d_out;

    // ws layout: proj (VP*1024 bf16 = 102.4MB) | em_f (8.4MB f32) |
    //            em_b (8.4MB f32) | Bb (256KB bf16).  Total ~119.5MB.
    const long long ROWS = (long long)B_ * T_;     // 65536
    __hip_bfloat16* proj = (__hip_bfloat16*)d_ws;
    float* em_f  = (float*)(proj + (long long)VP * 1024);
    float* em_bw = em_f + ROWS * K_;
    __hip_bfloat16* Bb = (__hip_bfloat16*)(em_bw + ROWS * K_);

    hipLaunchKernelGGL(pack_b_kernel, dim3(1024), dim3(128), 0, stream,
                       Wk_f, Wk_b, Bb);
    hipLaunchKernelGGL(proj_mfma_kernel, dim3((VP + 63) / 64), dim3(512), 0, stream,
                       emb, Bb, b_f, b_b, proj);
    hipLaunchKernelGGL(lstm_kernel, dim3(64), dim3(512), 0, stream,
                       proj, tokens, Wr_f, Wr_b, ck, em_f, em_bw);
    hipLaunchKernelGGL(crf_kernel, dim3(B_), dim3(64), 0, stream,
                       em_f, em_bw, cb, trans, out);
}

// Round 20
// 512.417 us; speedup vs baseline: 1.0955x; 1.0955x over previous
//
#include <hip/hip_runtime.h>
#include <hip/hip_bf16.h>

// Problem constants: B=128, T=512, V=50000, E=100, U=128, K=32
#define B_  128
#define T_  512
#define V_  50000
#define VP  50016   // V padded to 32
#define E_  100
#define U_  128
#define K_  32
#define G4  512   // 4*U
#define KP  128   // padded K for MFMA GEMM

typedef _Float16 h2_t __attribute__((ext_vector_type(2)));
typedef _Float16 f16x8 __attribute__((ext_vector_type(8)));
typedef __fp16   h2raw_t __attribute__((ext_vector_type(2)));
typedef short    bf16x8 __attribute__((ext_vector_type(8)));
typedef float    f32x4  __attribute__((ext_vector_type(4)));

// LDS-only barrier (T4): orders LDS ops without draining vmem.
#define LGKM_BARRIER() do {                                   \
    asm volatile("s_waitcnt lgkmcnt(0)" ::: "memory");        \
    __builtin_amdgcn_s_barrier();                             \
    asm volatile("" ::: "memory");                            \
} while (0)

__device__ __forceinline__ h2_t pk2(float a, float b) {
    h2raw_t r = __builtin_amdgcn_cvt_pkrtz(a, b);
    union { h2raw_t r; h2_t h; } u; u.r = r; return u.h;
}

#if __has_builtin(__builtin_amdgcn_rcpf)
__device__ __forceinline__ float rcp_f(float x) { return __builtin_amdgcn_rcpf(x); }
#else
__device__ __forceinline__ float rcp_f(float x) { return 1.f / x; }
#endif

__device__ __forceinline__ unsigned short bf16_bits(float v) {
    __hip_bfloat16 b = __float2bfloat16(v);
    union { __hip_bfloat16 b; unsigned short s; } u; u.b = b; return u.s;
}
__device__ __forceinline__ float bf2f(unsigned short u) {
    union { unsigned int i; float f; } x; x.i = ((unsigned int)u) << 16; return x.f;
}

// ---------------------------------------------------------------------------
// Kernel A0: pack Bb[n][k] (n-major, K padded to 128, bf16) from Wk_f|Wk_b.
// ---------------------------------------------------------------------------
__global__ __launch_bounds__(128) void pack_b_kernel(
    const float* __restrict__ Wk_f, const float* __restrict__ Wk_b,
    __hip_bfloat16* __restrict__ Bb)
{
    const int n = blockIdx.x;     // 0..1023
    const int k = threadIdx.x;    // 0..127
    float v = 0.f;
    if (k < E_) v = (n < 512) ? Wk_f[k * 512 + n] : Wk_b[k * 512 + (n - 512)];
    Bb[n * KP + k] = __float2bfloat16(v);
}

// ---------------------------------------------------------------------------
// Kernel A: proj[v][1024] = emb[v] @ [Wk_f | Wk_b] + [b_f | b_b], bf16.
//   (R13/R17 measured-best form: 64 rows/block, aliased A_st/C_lds,
//   4 n-groups, LDS C-epilogue with coalesced dword stores, lgkm-only
//   barriers. All structural deviations (R8/R11/R19) cost ~50 us.)
// ---------------------------------------------------------------------------
__global__ __launch_bounds__(512, 1) void proj_mfma_kernel(
    const float* __restrict__ emb,
    const __hip_bfloat16* __restrict__ Bb,
    const float* __restrict__ b_f, const float* __restrict__ b_b,
    __hip_bfloat16* __restrict__ proj)
{
    const int r0   = blockIdx.x * 64;
    const int tid  = threadIdx.x;
    const int wv   = tid >> 6;
    const int lane = tid & 63;
    const int quad = lane >> 4;
    const int l16  = lane & 15;
    const int mh   = wv >> 2;      // m-half: rows [mh*32, mh*32+32)
    const int cg   = wv & 3;       // col group: cols [cg*64, cg*64+64)

    __shared__ __align__(16) float C_lds[64][268];          // 68.6 KB
    unsigned short* A_st = (unsigned short*)&C_lds[0][0];   // [64][136] alias

    for (int idx = tid; idx < 64 * 64; idx += 512) {
        int r = idx >> 6, kk = idx & 63;
        int vr = r0 + r; if (vr >= V_) vr = V_ - 1;   // clamp: no OOB reads
        unsigned int w = 0;
        if (kk < 50) {
            float2 v = *(const float2*)(emb + (long long)vr * E_ + 2 * kk);
            w = ((unsigned int)bf16_bits(v.y) << 16) | bf16_bits(v.x);
        }
        *(unsigned int*)&A_st[r * 136 + 2 * kk] = w;
    }
    LGKM_BARRIER();

    bf16x8 af[2][4];
    #pragma unroll
    for (int mt = 0; mt < 2; ++mt)
        #pragma unroll
        for (int kc = 0; kc < 4; ++kc)
            af[mt][kc] = *(const bf16x8*)&A_st[(mh * 32 + mt * 16 + l16) * 136 +
                                               kc * 32 + quad * 8];
    LGKM_BARRIER();

    const unsigned short* Bu = (const unsigned short*)Bb;

    for (int ng = 0; ng < 4; ++ng) {
        const int n0 = ng * 256;

        bf16x8 bfr[4][4];
        #pragma unroll
        for (int nt = 0; nt < 4; ++nt)
            #pragma unroll
            for (int kc = 0; kc < 4; ++kc)
                bfr[nt][kc] = *(const bf16x8*)(Bu +
                    (n0 + cg * 64 + nt * 16 + l16) * KP + kc * 32 + quad * 8);

        f32x4 acc[2][4];
        #pragma unroll
        for (int mt = 0; mt < 2; ++mt)
            #pragma unroll
            for (int nt = 0; nt < 4; ++nt)
                acc[mt][nt] = (f32x4){0.f, 0.f, 0.f, 0.f};

        #pragma unroll
        for (int mt = 0; mt < 2; ++mt)
            #pragma unroll
            for (int nt = 0; nt < 4; ++nt)
                #pragma unroll
                for (int kc = 0; kc < 4; ++kc)
                    acc[mt][nt] = __builtin_amdgcn_mfma_f32_16x16x32_bf16(
                        af[mt][kc], bfr[nt][kc], acc[mt][nt], 0, 0, 0);

        #pragma unroll
        for (int mt = 0; mt < 2; ++mt)
            #pragma unroll
            for (int nt = 0; nt < 4; ++nt)
                #pragma unroll
                for (int v = 0; v < 4; ++v)
                    C_lds[mh * 32 + mt * 16 + quad * 4 + v]
                         [cg * 64 + nt * 16 + l16] = acc[mt][nt][v];
        LGKM_BARRIER();

        const float* bias = (n0 < 512) ? b_f : b_b;
        const int nbase = n0 & 511;
        for (int idx = tid; idx < 64 * 128; idx += 512) {
            int r = idx >> 7, cc = (idx & 127) * 2;
            float v0 = C_lds[r][cc]     + bias[nbase + cc];
            float v1 = C_lds[r][cc + 1] + bias[nbase + cc + 1];
            unsigned int w = ((unsigned int)bf16_bits(v1) << 16) | bf16_bits(v0);
            int row = r0 + r; if (row >= VP) row = VP - 1;  // pad row, never read
            *(unsigned int*)(proj + (long long)row * 1024 + n0 + cc) = w;
        }
        LGKM_BARRIER();
    }
}

// ---------------------------------------------------------------------------
// Kernel B: LSTM with fused em partials (R17-EXACT: ring 16, em burst every
//   2 groups on waves 0-3, xk added after MFMA — measured 257 us / 514 total).
// ---------------------------------------------------------------------------
__device__ __forceinline__ float sigmoid_f(float x) {
    return rcp_f(1.f + __expf(-x));
}
__device__ __forceinline__ float tanh_f(float x) {
    return 1.f - 2.f * rcp_f(__expf(2.f * x) + 1.f);
}

__global__ __launch_bounds__(512, 1) void lstm_kernel(
    const __hip_bfloat16* __restrict__ proj,
    const int* __restrict__ tokens,
    const float* __restrict__ Wr_f, const float* __restrict__ Wr_b,
    const float* __restrict__ ck,
    float* __restrict__ em_f, float* __restrict__ em_bw)
{
    const int bid  = blockIdx.x;      // 0..63
    const int dir  = bid >> 5;
    const int b0   = (bid & 31) * 4;  // this block's 4 chains
    const int tid  = threadIdx.x;
    const int w    = tid >> 6;        // wave 0..7 -> units [16w, 16w+16)
    const int lane = tid & 63;
    const int quad = lane >> 4;       // = chain index within block
    const int l16  = lane & 15;
    const int unit = 16 * w + l16;

    const float* Wr = dir ? Wr_b : Wr_f;
    float* eout = dir ? em_bw : em_f;

    // B-frags: wb[g][kc]; element j = Wr[kc*32+quad*8+j][g*128 + unit]
    union uf16 { f16x8 v; h2_t p[4]; };
    f16x8 wb[4][4];
    #pragma unroll
    for (int gq = 0; gq < 4; ++gq) {
        const int col = gq * 128 + unit;
        #pragma unroll
        for (int kc = 0; kc < 4; ++kc) {
            const int k0 = kc * 32 + quad * 8;
            uf16 u;
            #pragma unroll
            for (int jj = 0; jj < 4; ++jj)
                u.p[jj] = pk2(Wr[(k0 + 2 * jj)     * G4 + col],
                              Wr[(k0 + 2 * jj + 1) * G4 + col]);
            wb[gq][kc] = u.v;
        }
    }

    // ck B-frags for the em MFMA (waves 0-3): k-half kh = w&1;
    // col = kh*16+l16; k = dir*128 + (kc*32+quad*8+j). ck is [256][32].
    f16x8 ckb[4];
    const int kh = w & 1;
    const int gs = w >> 1;            // group-pair half (0 -> t4-1, 1 -> t4)
    if (w < 4) {
        #pragma unroll
        for (int kc = 0; kc < 4; ++kc) {
            const int k0 = dir * 128 + kc * 32 + quad * 8;
            uf16 u;
            #pragma unroll
            for (int jj = 0; jj < 4; ++jj)
                u.p[jj] = pk2(ck[(k0 + 2 * jj)     * K_ + kh * 16 + l16],
                              ck[(k0 + 2 * jj + 1) * K_ + kh * 16 + l16]);
            ckb[kc] = u.v;
        }
    }

    // h ring: [16][chain][144 f16] (288B rows ≡ 8 banks); step t reads buf
    // t&15, writes buf (t+1)&15; group g's h lands in bufs (4g+1..4g+4)&15.
    __shared__ __align__(16) _Float16      h_lds[16][4][144];  // 18.4 KB
    // xk double-buffer: [buf][chain][520 u16] (1040B rows)
    __shared__ __align__(16) unsigned short xkb[2][4][520];    // 8.3 KB
    // token table for this block's 4 chains, time-reversed for dir=1
    __shared__ unsigned short tok_lds[4][512];                 // 4 KB

    for (int idx = tid; idx < 4 * 512; idx += 512) {
        int chain = idx >> 9, tt = idx & 511;
        int tsrc = dir ? (T_ - 1 - tt) : tt;
        tok_lds[chain][tt] = (unsigned short)tokens[(b0 + chain) * T_ + tsrc];
    }
    for (int idx = tid; idx < 4 * 144; idx += 512)
        ((_Float16*)h_lds[0])[idx] = (_Float16)0.f;
    __syncthreads();

    // staging mapping: chain sc, dword-column sj (cols 2sj,2sj+1 and +256)
    const int sc = tid >> 7;          // 0..3
    const int sj = tid & 127;         // 0..127
    const unsigned short* prbase = (const unsigned short*)proj + dir * 512;

    // prefetch ring: v[d] holds the step whose index ≡ d (mod 4)
    int v[4][2];
    #pragma unroll
    for (int d = 0; d < 4; ++d) {
        int tk = tok_lds[sc][d];
        const unsigned int* p32 = (const unsigned int*)(prbase + (size_t)tk * 1024);
        v[d][0] = p32[sj];
        v[d][1] = p32[sj + 128];
    }
    // publish step 0 into xkb[0]
    *(unsigned int*)&xkb[0][sc][2 * sj]       = v[0][0];
    *(unsigned int*)&xkb[0][sc][2 * sj + 256] = v[0][1];
    __syncthreads();

    float c = 0.f;

    for (int t4 = 0; t4 < T_ / 4; ++t4) {
        #pragma unroll
        for (int u = 0; u < 4; ++u) {
            const int t  = t4 * 4 + u;
            const int cb = u & 1, nb = cb ^ 1;   // xk parity buffers
            const int hr = t & 15;               // h ring read buf
            const int hw = (t + 1) & 15;         // h ring write buf

            // (1) LDS reads: A-frag (4 chains via l16>>2) + xk (4 gates)
            f16x8 a[4];
            #pragma unroll
            for (int kc = 0; kc < 4; ++kc)
                a[kc] = *(const f16x8*)&h_lds[hr][l16 >> 2][kc * 32 + quad * 8];
            unsigned short xk[4];
            #pragma unroll
            for (int gq = 0; gq < 4; ++gq)
                xk[gq] = xkb[cb][quad][gq * 128 + unit];

            // (2) issue staging loads for step t+4 into v[u]
            {
                int tnx = t + 4; if (tnx > T_ - 1) tnx = T_ - 1;
                int tk = tok_lds[sc][tnx];
                const unsigned int* p32 =
                    (const unsigned int*)(prbase + (size_t)tk * 1024);
                v[u][0] = p32[sj];
                v[u][1] = p32[sj + 128];
            }

            // (3) MFMA: z for 4 chains (chain = C-row>>2 = quad)
            f32x4 acc[4];
            #pragma unroll
            for (int gq = 0; gq < 4; ++gq)
                acc[gq] = (f32x4){0.f, 0.f, 0.f, 0.f};
            #pragma unroll
            for (int gq = 0; gq < 4; ++gq)
                #pragma unroll
                for (int kc = 0; kc < 4; ++kc)
                    acc[gq] = __builtin_amdgcn_mfma_f32_16x16x32_f16(
                        a[kc], wb[gq][kc], acc[gq], 0, 0, 0);

            // (4) gates: ONE (chain=quad, unit) per lane
            float zi = acc[0][0] + bf2f(xk[0]);
            float zf = acc[1][0] + bf2f(xk[1]);
            float zg = acc[2][0] + bf2f(xk[2]);
            float zo = acc[3][0] + bf2f(xk[3]);
            c = sigmoid_f(zf) * c + sigmoid_f(zi) * tanh_f(zg);
            float h = sigmoid_f(zo) * tanh_f(c);
            h_lds[hw][quad][unit] = (_Float16)h;

            // (5) publish v[(u+1)&3] (loaded 3 steps ago) for step t+1
            {
                const int pw = (u + 1) & 3;
                *(unsigned int*)&xkb[nb][sc][2 * sj]       = v[pw][0];
                *(unsigned int*)&xkb[nb][sc][2 * sj + 256] = v[pw][1];
            }

            // (6) LDS-only barrier: vmem stays in flight (T4)
            LGKM_BARRIER();
        }

        // ---- fused em partial, every 2 groups on waves 0-3 ----
        // wave w: group g' = t4-1+gs, k-half kh. Reads bufs
        // (4g'+1..4g'+4)&15 — not rewritten for 2 more groups.
        if ((t4 & 1) && w < 4) {
            const int gp   = t4 - 1 + gs;
            const int d    = l16 >> 2;           // step-in-group of A row
            const int ch   = l16 & 3;            // chain of A row
            const int rbuf = (4 * gp + 1 + d) & 15;
            f16x8 ea[4];
            #pragma unroll
            for (int kc = 0; kc < 4; ++kc)
                ea[kc] = *(const f16x8*)&h_lds[rbuf][ch][kc * 32 + quad * 8];
            f32x4 e = (f32x4){0.f, 0.f, 0.f, 0.f};
            #pragma unroll
            for (int kc = 0; kc < 4; ++kc)
                e = __builtin_amdgcn_mfma_f32_16x16x32_f16(
                    ea[kc], ckb[kc], e, 0, 0, 0);
            // C: row = quad*4+v -> (step d=quad, chain=v); col = l16
            const int step = gp * 4 + quad;
            const int tte  = dir ? (T_ - 1 - step) : step;
            #pragma unroll
            for (int vv = 0; vv < 4; ++vv)
                eout[((size_t)(b0 + vv) * T_ + tte) * K_ + (kh << 4) + l16] =
                    e[vv];
        }
    }
}

// ---------------------------------------------------------------------------
// Kernel D: CRF logZ — linear-space chain, tree-reassociated alpha update
//   (R12/R14 measured-good form: 16 shfl + 4x4-deep fma tree + xor combine).
// ---------------------------------------------------------------------------
#define PF_ 8
__global__ __launch_bounds__(64) void crf_kernel(
    const float* __restrict__ em_f, const float* __restrict__ em_bw,
    const float* __restrict__ cb,
    const float* __restrict__ trans,
    float* __restrict__ out)
{
    const int b    = blockIdx.x;
    const int lane = threadIdx.x;
    const int k    = lane & 31;
    const int half = lane >> 5;

    float etr[16];
    #pragma unroll
    for (int i = 0; i < 16; ++i)
        etr[i] = __expf(trans[(half * 16 + i) * K_ + k]);

    const float cbk = cb[k];
    const float* ef = em_f  + (long long)b * T_ * K_;
    const float* eb = em_bw + (long long)b * T_ * K_;

    float ep[PF_];
    #pragma unroll
    for (int d = 0; d < PF_; ++d)
        ep[d] = ef[d * K_ + k] + eb[d * K_ + k] + cbk;

    float w = 0.f;    // linear-space alpha, scaled
    float L = 0.f;    // accumulated log-scale
    for (int tb = 0; tb < T_; tb += PF_) {
        float en[PF_];
        if (tb + PF_ < T_) {
            #pragma unroll
            for (int d = 0; d < PF_; ++d)
                en[d] = ef[(tb + PF_ + d) * K_ + k] +
                        eb[(tb + PF_ + d) * K_ + k] + cbk;
        } else {
            #pragma unroll
            for (int d = 0; d < PF_; ++d) en[d] = 0.f;
        }

        float eem[PF_];
        #pragma unroll
        for (int d = 0; d < PF_; ++d) eem[d] = __expf(ep[d]);

        #pragma unroll
        for (int d = 0; d < PF_; ++d) {
            if (tb + d == 0) {
                w = eem[d];
            } else {
                // 4 independent 4-deep fma chains (tree combine)
                float a0 = 0.f, a1 = 0.f, a2 = 0.f, a3 = 0.f;
                #pragma unroll
                for (int i = 0; i < 4; ++i)
                    a0 = fmaf(__shfl(w, half * 16 + i,      64), etr[i],      a0);
                #pragma unroll
                for (int i = 0; i < 4; ++i)
                    a1 = fmaf(__shfl(w, half * 16 + 4 + i,  64), etr[4 + i],  a1);
                #pragma unroll
                for (int i = 0; i < 4; ++i)
                    a2 = fmaf(__shfl(w, half * 16 + 8 + i,  64), etr[8 + i],  a2);
                #pragma unroll
                for (int i = 0; i < 4; ++i)
                    a3 = fmaf(__shfl(w, half * 16 + 12 + i, 64), etr[12 + i], a3);
                float acc = (a0 + a1) + (a2 + a3);
                acc += __shfl_xor(acc, 32, 64);
                w = acc * eem[d];
            }
        }

        {
            float w0 = __shfl(w, 0, 64);
            w *= rcp_f(w0);
            L += __logf(w0);
        }

        #pragma unroll
        for (int d = 0; d < PF_; ++d) ep[d] = en[d];
    }

    float s = w;
    #pragma unroll
    for (int d = 1; d < 32; d <<= 1)
        s += __shfl_xor(s, d, 64);
    if (lane == 0) out[b] = L + __logf(s);
}

// ---------------------------------------------------------------------------
extern "C" void kernel_launch(void* const* d_in, const int* in_sizes, int n_in,
                              void* d_out, int out_size, void* d_ws, size_t ws_size,
                              hipStream_t stream)
{
    const int*   tokens = (const int*)  d_in[0];
    const float* emb    = (const float*)d_in[1];
    const float* Wk_f   = (const float*)d_in[2];
    const float* Wr_f   = (const float*)d_in[3];
    const float* b_f    = (const float*)d_in[4];
    const float* Wk_b   = (const float*)d_in[5];
    const float* Wr_b   = (const float*)d_in[6];
    const float* b_b    = (const float*)d_in[7];
    const float* ck     = (const float*)d_in[8];
    const float* cb     = (const float*)d_in[9];
    const float* trans  = (const float*)d_in[10];
    float* out = (float*)d_out;

    // ws layout: proj (VP*1024 bf16 = 102.4MB) | em_f (8.4MB f32) |
    //            em_b (8.4MB f32) | Bb (256KB bf16).  Total ~119.5MB.
    const long long ROWS = (long long)B_ * T_;     // 65536
    __hip_bfloat16* proj = (__hip_bfloat16*)d_ws;
    float* em_f  = (float*)(proj + (long long)VP * 1024);
    float* em_bw = em_f + ROWS * K_;
    __hip_bfloat16* Bb = (__hip_bfloat16*)(em_bw + ROWS * K_);

    hipLaunchKernelGGL(pack_b_kernel, dim3(1024), dim3(128), 0, stream,
                       Wk_f, Wk_b, Bb);
    hipLaunchKernelGGL(proj_mfma_kernel, dim3((VP + 63) / 64), dim3(512), 0, stream,
                       emb, Bb, b_f, b_b, proj);
    hipLaunchKernelGGL(lstm_kernel, dim3(64), dim3(512), 0, stream,
                       proj, tokens, Wr_f, Wr_b, ck, em_f, em_bw);
    hipLaunchKernelGGL(crf_kernel, dim3(B_), dim3(64), 0, stream,
                       em_f, em_bw, cb, trans, out);
}